// Round 4
// baseline (473.872 us; speedup 1.0000x reference)
//
#include <hip/hip_runtime.h>
#include <hip/hip_bf16.h>

#define HID 1024
#define NHEAD 16
#define HDIM 64
#define BB 4
#define SS 2048
#define MTOK (BB * SS)   // 8192 tokens

typedef __attribute__((ext_vector_type(8))) short bf16x8;
typedef __attribute__((ext_vector_type(4))) float f32x4;

__device__ __forceinline__ unsigned short f2bs(float f) {
  __hip_bfloat16 h = __float2bfloat16(f);
  unsigned short u;
  __builtin_memcpy(&u, &h, 2);
  return u;
}

// pack two fp32 -> two bf16 in one dword, round-half-up (<=0.5 ulp)
__device__ __forceinline__ unsigned int pkbf(float a, float b) {
  unsigned int ua, ub;
  __builtin_memcpy(&ua, &a, 4);
  __builtin_memcpy(&ub, &b, 4);
  return ((ua + 0x8000u) >> 16) | ((ub + 0x8000u) & 0xFFFF0000u);
}

// async global->LDS, 16B per lane. LDS dest = wave-uniform base + lane*16.
__device__ __forceinline__ void gload16(const void* g, void* l) {
  __builtin_amdgcn_global_load_lds((__attribute__((address_space(1))) const void*)g,
                                   (__attribute__((address_space(3))) void*)l, 16, 0, 0);
}

// ===================== conversion pass (fp32 -> bf16) =====================
__global__ __launch_bounds__(256) void cvt_all(
    const float* __restrict__ s_q, const float* __restrict__ s_k, const float* __restrict__ s_v,
    const float* __restrict__ wq, const float* __restrict__ wk, const float* __restrict__ wv,
    const float* __restrict__ wo,
    unsigned short* __restrict__ xq, unsigned short* __restrict__ xk, unsigned short* __restrict__ xv,
    unsigned short* __restrict__ wcat, unsigned short* __restrict__ wobf) {
  const int bid = blockIdx.x;
  const float* src;
  unsigned short* dst;
  size_t off;
  if (bid < 3072) {
    int s = bid >> 10;
    src = (s == 0 ? s_q : (s == 1 ? s_k : s_v));
    dst = (s == 0 ? xq : (s == 1 ? xk : xv));
    off = (size_t)(bid & 1023) * 8192;
  } else {
    int s = (bid - 3072) >> 7;
    src = (s == 0 ? wq : (s == 1 ? wk : (s == 2 ? wv : wo)));
    dst = (s < 3 ? wcat + (size_t)s * HID * HID : wobf);
    off = (size_t)((bid - 3072) & 127) * 8192;
  }
  src += off;
  dst += off;
  const int t = threadIdx.x;
#pragma unroll
  for (int i = 0; i < 8; i++) {
    float4 f = *(const float4*)(src + (size_t)(i * 256 + t) * 4);
    ushort4 h;
    h.x = f2bs(f.x); h.y = f2bs(f.y); h.z = f2bs(f.z); h.w = f2bs(f.w);
    *(ushort4*)(dst + (size_t)(i * 256 + t) * 4) = h;
  }
}

// ===================== fused QKV GEMM (bf16, global_load_lds) =====================
__global__ __launch_bounds__(256) void qkv_gemm(
    const unsigned short* __restrict__ xq, const unsigned short* __restrict__ xk,
    const unsigned short* __restrict__ xv, const unsigned short* __restrict__ wcat,
    const float* __restrict__ bq, const float* __restrict__ bk, const float* __restrict__ bv,
    unsigned short* __restrict__ qhm, unsigned short* __restrict__ khm,
    unsigned short* __restrict__ vth) {
  __shared__ unsigned short As[128 * 32];
  __shared__ unsigned short Bs[128 * 32];
  const int bid = blockIdx.x;
  const int mt = bid / 24, nt = bid % 24;
  const int sel = nt >> 3;
  const int m0 = mt << 7, n0 = (nt & 7) << 7;
  const int tid = threadIdx.x;
  const int lane = tid & 63, wave = tid >> 6;
  const int quad = lane >> 4, l15 = lane & 15;
  const int wm = ((wave >> 1) << 6), wn = ((wave & 1) << 6);

  const unsigned short* A = (sel == 0 ? xq : (sel == 1 ? xk : xv));
  const unsigned short* W = wcat + (size_t)sel * HID * HID;
  const float* bias = (sel == 0 ? bq : (sel == 1 ? bk : bv));

  const int c0 = wave * 128 + lane;
  const int c1 = c0 + 64;
  const unsigned short* gA0 = A + (size_t)(m0 + (c0 >> 2)) * HID + (c0 & 3) * 8;
  const unsigned short* gA1 = A + (size_t)(m0 + (c1 >> 2)) * HID + (c1 & 3) * 8;
  const unsigned short* gB0 = W + (size_t)(n0 + (c0 >> 2)) * HID + (c0 & 3) * 8;
  const unsigned short* gB1 = W + (size_t)(n0 + (c1 >> 2)) * HID + (c1 & 3) * 8;
  unsigned short* lA0 = As + (size_t)(wave * 128) * 8;
  unsigned short* lA1 = lA0 + 64 * 8;
  unsigned short* lB0 = Bs + (size_t)(wave * 128) * 8;
  unsigned short* lB1 = lB0 + 64 * 8;

  f32x4 acc[4][4] = {};

  for (int k0 = 0; k0 < HID; k0 += 32) {
    __syncthreads();
    gload16(gA0 + k0, lA0);
    gload16(gA1 + k0, lA1);
    gload16(gB0 + k0, lB0);
    gload16(gB1 + k0, lB1);
    __syncthreads();
    bf16x8 af[4], bfr[4];
#pragma unroll
    for (int i = 0; i < 4; i++)
      af[i] = *(const bf16x8*)(As + (wm + i * 16 + l15) * 32 + quad * 8);
#pragma unroll
    for (int j = 0; j < 4; j++)
      bfr[j] = *(const bf16x8*)(Bs + (wn + j * 16 + l15) * 32 + quad * 8);
#pragma unroll
    for (int i = 0; i < 4; i++)
#pragma unroll
      for (int j = 0; j < 4; j++)
        acc[i][j] = __builtin_amdgcn_mfma_f32_16x16x32_bf16(af[i], bfr[j], acc[i][j], 0, 0, 0);
  }

#pragma unroll
  for (int j = 0; j < 4; j++) {
    const int col = n0 + wn + j * 16 + l15;
    const float bvv = bias[col];
    const int hh = col >> 6, d = col & 63;
    if (sel < 2) {
      unsigned short* outp = (sel == 0 ? qhm : khm);
#pragma unroll
      for (int i = 0; i < 4; i++) {
        const int row0 = m0 + wm + i * 16 + quad * 4;
        const int bb = row0 >> 11, s0 = row0 & 2047;
        const size_t base = ((size_t)(bb * NHEAD + hh)) * SS * HDIM + (size_t)s0 * HDIM + d;
#pragma unroll
        for (int r = 0; r < 4; r++)
          outp[base + (size_t)r * HDIM] = f2bs(acc[i][j][r] + bvv);
      }
    } else {
#pragma unroll
      for (int i = 0; i < 4; i++) {
        const int row0 = m0 + wm + i * 16 + quad * 4;
        const int bb = row0 >> 11, s0 = row0 & 2047;
        ushort4 pk;
        pk.x = f2bs(acc[i][j][0] + bvv);
        pk.y = f2bs(acc[i][j][1] + bvv);
        pk.z = f2bs(acc[i][j][2] + bvv);
        pk.w = f2bs(acc[i][j][3] + bvv);
        *(ushort4*)&vth[((size_t)(bb * NHEAD + hh)) * HDIM * SS + (size_t)d * SS + s0] = pk;
      }
    }
  }
}

// ===================== out-proj GEMM (bf16 A/W, fp32 out) =====================
__global__ __launch_bounds__(256) void out_gemm(const unsigned short* __restrict__ A,
                                                const unsigned short* __restrict__ W,
                                                const float* __restrict__ bias,
                                                float* __restrict__ C) {
  __shared__ unsigned short As[128 * 32];
  __shared__ unsigned short Bs[128 * 32];
  const int bid = blockIdx.x;
  const int mt = bid >> 3, nt = bid & 7;
  const int m0 = mt << 7, n0 = nt << 7;
  const int tid = threadIdx.x;
  const int lane = tid & 63, wave = tid >> 6;
  const int quad = lane >> 4, l15 = lane & 15;
  const int wm = ((wave >> 1) << 6), wn = ((wave & 1) << 6);

  const int c0 = wave * 128 + lane;
  const int c1 = c0 + 64;
  const unsigned short* gA0 = A + (size_t)(m0 + (c0 >> 2)) * HID + (c0 & 3) * 8;
  const unsigned short* gA1 = A + (size_t)(m0 + (c1 >> 2)) * HID + (c1 & 3) * 8;
  const unsigned short* gB0 = W + (size_t)(n0 + (c0 >> 2)) * HID + (c0 & 3) * 8;
  const unsigned short* gB1 = W + (size_t)(n0 + (c1 >> 2)) * HID + (c1 & 3) * 8;
  unsigned short* lA0 = As + (size_t)(wave * 128) * 8;
  unsigned short* lA1 = lA0 + 64 * 8;
  unsigned short* lB0 = Bs + (size_t)(wave * 128) * 8;
  unsigned short* lB1 = lB0 + 64 * 8;

  f32x4 acc[4][4] = {};

  for (int k0 = 0; k0 < HID; k0 += 32) {
    __syncthreads();
    gload16(gA0 + k0, lA0);
    gload16(gA1 + k0, lA1);
    gload16(gB0 + k0, lB0);
    gload16(gB1 + k0, lB1);
    __syncthreads();
    bf16x8 af[4], bfr[4];
#pragma unroll
    for (int i = 0; i < 4; i++)
      af[i] = *(const bf16x8*)(As + (wm + i * 16 + l15) * 32 + quad * 8);
#pragma unroll
    for (int j = 0; j < 4; j++)
      bfr[j] = *(const bf16x8*)(Bs + (wn + j * 16 + l15) * 32 + quad * 8);
#pragma unroll
    for (int i = 0; i < 4; i++)
#pragma unroll
      for (int j = 0; j < 4; j++)
        acc[i][j] = __builtin_amdgcn_mfma_f32_16x16x32_bf16(af[i], bfr[j], acc[i][j], 0, 0, 0);
  }

#pragma unroll
  for (int j = 0; j < 4; j++) {
    const int col = n0 + wn + j * 16 + l15;
    const float bvv = bias[col];
#pragma unroll
    for (int i = 0; i < 4; i++) {
      const int row0 = m0 + wm + i * 16 + quad * 4;
#pragma unroll
      for (int r = 0; r < 4; r++)
        C[(size_t)(row0 + r) * HID + col] = acc[i][j][r] + bvv;
    }
  }
}

// ===================== legacy fp32-staging GEMM (fallback plan) =====================
__device__ __forceinline__ void stage_tile(unsigned short* s, const float* g, int ldg, int tid) {
#pragma unroll
  for (int i = 0; i < 4; i++) {
    int c = i * 256 + tid;
    int row = c >> 3;
    int col = (c & 7) * 4;
    const float4 v = *(const float4*)(g + (size_t)row * ldg + col);
    ushort4 hv;
    hv.x = f2bs(v.x); hv.y = f2bs(v.y); hv.z = f2bs(v.z); hv.w = f2bs(v.w);
    *(ushort4*)(s + c * 4) = hv;
  }
}
__device__ __forceinline__ void stage_tile(unsigned short* s, const unsigned short* g, int ldg, int tid) {
#pragma unroll
  for (int i = 0; i < 2; i++) {
    int c = i * 256 + tid;
    int row = c >> 2;
    int col = (c & 3) * 8;
    const uint4 v = *(const uint4*)(g + (size_t)row * ldg + col);
    *(uint4*)(s + c * 8) = v;
  }
}

template <typename TA, int MODE>
__global__ __launch_bounds__(256) void gemm_bt(const TA* __restrict__ A, const float* __restrict__ W,
                                               const float* __restrict__ bias, void* __restrict__ Cp,
                                               int M, int N, int K) {
  __shared__ unsigned short As[128 * 32];
  __shared__ unsigned short Bs[128 * 32];
  const int nb = N >> 7;
  const int m0 = (blockIdx.x / nb) << 7;
  const int n0 = (blockIdx.x % nb) << 7;
  const int tid = threadIdx.x;
  const int lane = tid & 63, wave = tid >> 6;
  const int quad = lane >> 4, l15 = lane & 15;
  const int wm = ((wave >> 1) << 6), wn = ((wave & 1) << 6);

  f32x4 acc[4][4] = {};

  for (int k0 = 0; k0 < K; k0 += 32) {
    __syncthreads();
    stage_tile(As, A + (size_t)m0 * K + k0, K, tid);
    stage_tile(Bs, W + (size_t)n0 * K + k0, K, tid);
    __syncthreads();
    bf16x8 af[4], bfr[4];
#pragma unroll
    for (int i = 0; i < 4; i++)
      af[i] = *(const bf16x8*)(As + (wm + i * 16 + l15) * 32 + quad * 8);
#pragma unroll
    for (int j = 0; j < 4; j++)
      bfr[j] = *(const bf16x8*)(Bs + (wn + j * 16 + l15) * 32 + quad * 8);
#pragma unroll
    for (int i = 0; i < 4; i++)
#pragma unroll
      for (int j = 0; j < 4; j++)
        acc[i][j] = __builtin_amdgcn_mfma_f32_16x16x32_bf16(af[i], bfr[j], acc[i][j], 0, 0, 0);
  }

#pragma unroll
  for (int j = 0; j < 4; j++) {
    const int col = n0 + wn + j * 16 + l15;
    const float bvv = bias[col];
    if constexpr (MODE == 0) {
      float* outp = (float*)Cp;
#pragma unroll
      for (int i = 0; i < 4; i++) {
        const int row0 = m0 + wm + i * 16 + quad * 4;
#pragma unroll
        for (int r = 0; r < 4; r++)
          outp[(size_t)(row0 + r) * N + col] = acc[i][j][r] + bvv;
      }
    } else if constexpr (MODE == 1) {
      unsigned short* outp = (unsigned short*)Cp;
      const int hh = col >> 6, d = col & 63;
#pragma unroll
      for (int i = 0; i < 4; i++) {
        const int row0 = m0 + wm + i * 16 + quad * 4;
        const int bb = row0 >> 11, s0 = row0 & 2047;
        const size_t base = ((size_t)(bb * NHEAD + hh)) * SS * HDIM + (size_t)s0 * HDIM + d;
#pragma unroll
        for (int r = 0; r < 4; r++)
          outp[base + (size_t)r * HDIM] = f2bs(acc[i][j][r] + bvv);
      }
    } else {
      unsigned short* outp = (unsigned short*)Cp;
      const int hh = col >> 6, d = col & 63;
#pragma unroll
      for (int i = 0; i < 4; i++) {
        const int row0 = m0 + wm + i * 16 + quad * 4;
        const int bb = row0 >> 11, s0 = row0 & 2047;
        ushort4 pk;
        pk.x = f2bs(acc[i][j][0] + bvv);
        pk.y = f2bs(acc[i][j][1] + bvv);
        pk.z = f2bs(acc[i][j][2] + bvv);
        pk.w = f2bs(acc[i][j][3] + bvv);
        *(ushort4*)&outp[((size_t)(bb * NHEAD + hh)) * HDIM * SS + (size_t)d * SS + s0] = pk;
      }
    }
  }
}

// ===================== flash attention v3 =====================
// 1024 blocks = (b, h, 128-row q tile); 4 waves x 2 sequential 16-row groups.
// K/V register-prefetch double buffer; constant-shift softmax (no max tracking);
// row-sum via ones-fragment MFMA.
#define KSTR 72
#define VSTR 136
#define PSTR 136

__global__ __launch_bounds__(256, 3) void attn_v3(const unsigned short* __restrict__ q,
                                                  const unsigned short* __restrict__ k,
                                                  const unsigned short* __restrict__ vt,
                                                  const float* __restrict__ mask,
                                                  unsigned short* __restrict__ ctx) {
  __shared__ unsigned short Ks[128 * KSTR];
  __shared__ unsigned short Vts[64 * VSTR];
  __shared__ unsigned short Ps[4 * 16 * PSTR];
  __shared__ float Ms[128];

  const int bid = blockIdx.x;
  const int qt = bid & 15;            // S/128 = 16 q tiles
  const int h  = (bid >> 4) & 15;
  const int b  = bid >> 8;
  const int bh = b * NHEAD + h;
  const int tid = threadIdx.x;
  const int wave = tid >> 6, lane = tid & 63;
  const int quad = lane >> 4, l15 = lane & 15;

  // Q fragments for both 16-row groups (B operand of S^T = K Q^T)
  bf16x8 qf[2][2];
#pragma unroll
  for (int g = 0; g < 2; g++) {
    const unsigned short* qb =
        q + ((size_t)bh * SS + qt * 128 + g * 64 + wave * 16 + l15) * HDIM;
    qf[g][0] = *(const bf16x8*)(qb + quad * 8);
    qf[g][1] = *(const bf16x8*)(qb + 32 + quad * 8);
  }

  f32x4 O[2][4] = {};
  f32x4 L[2] = {};

  bf16x8 ones;
#pragma unroll
  for (int i = 0; i < 8; i++) ones[i] = (short)0x3F80;   // bf16 1.0

  const unsigned short* kg0 = k + (size_t)bh * SS * HDIM;
  const unsigned short* vg0 = vt + (size_t)bh * HDIM * SS;
  unsigned short* pw = &Ps[wave * 16 * PSTR];

  // register prefetch buffers
  uint4 kreg[4], vreg[4];
  {
#pragma unroll
    for (int i = 0; i < 4; i++) {
      int c = i * 256 + tid;
      kreg[i] = *(const uint4*)(kg0 + c * 8);
      int row = c >> 4, col = (c & 15) * 8;
      vreg[i] = *(const uint4*)(vg0 + (size_t)row * SS + col);
    }
  }
  float mreg = 0.0f;
  if (tid < 128) mreg = mask[(size_t)b * SS + tid];

  for (int kb = 0; kb < SS / 128; kb++) {
    __syncthreads();  // all waves done reading previous Ks/Vts
    // commit prefetched tile to LDS
#pragma unroll
    for (int i = 0; i < 4; i++) {
      int c = i * 256 + tid;
      int row = c >> 3, col = (c & 7) * 8;
      *(uint4*)&Ks[row * KSTR + col] = kreg[i];
    }
#pragma unroll
    for (int i = 0; i < 4; i++) {
      int c = i * 256 + tid;
      int row = c >> 4, col = (c & 15) * 8;
      *(uint4*)&Vts[row * VSTR + col] = vreg[i];
    }
    if (tid < 128) Ms[tid] = (1.0f - mreg) * -10000.0f - 8.0f;  // mask add + const shift
    __syncthreads();

    // issue next tile's global loads (latency hidden behind compute below)
    if (kb + 1 < SS / 128) {
      const unsigned short* kg = kg0 + (size_t)(kb + 1) * 128 * HDIM;
      const unsigned short* vg = vg0 + (size_t)(kb + 1) * 128;
#pragma unroll
      for (int i = 0; i < 4; i++) {
        int c = i * 256 + tid;
        kreg[i] = *(const uint4*)(kg + c * 8);
        int row = c >> 4, col = (c & 15) * 8;
        vreg[i] = *(const uint4*)(vg + (size_t)row * SS + col);
      }
      if (tid < 128) mreg = mask[(size_t)b * SS + (kb + 1) * 128 + tid];
    }

#pragma unroll
    for (int g = 0; g < 2; g++) {
      // S^T = K Q^T : col=l15 (q), row=quad*4+r (kv within mt)
      f32x4 Sc[8];
#pragma unroll
      for (int mt = 0; mt < 8; mt++) {
        f32x4 z = {};
#pragma unroll
        for (int kc = 0; kc < 2; kc++) {
          bf16x8 kf = *(const bf16x8*)&Ks[(mt * 16 + l15) * KSTR + kc * 32 + quad * 8];
          z = __builtin_amdgcn_mfma_f32_16x16x32_bf16(kf, qf[g][kc], z, 0, 0, 0);
        }
        f32x4 mv = *(const f32x4*)&Ms[mt * 16 + quad * 4];
        Sc[mt] = z * 0.125f + mv;
      }
      // exp (no max tracking: constant shift already applied via Ms)
#pragma unroll
      for (int mt = 0; mt < 8; mt++)
#pragma unroll
        for (int r = 0; r < 4; r++) Sc[mt][r] = __expf(Sc[mt][r]);

      // P -> LDS (per-wave region, contiguous dword pairs)
#pragma unroll
      for (int mt = 0; mt < 8; mt++) {
        uint2 u;
        u.x = pkbf(Sc[mt][0], Sc[mt][1]);
        u.y = pkbf(Sc[mt][2], Sc[mt][3]);
        *(uint2*)&pw[l15 * PSTR + mt * 16 + quad * 4] = u;
      }

      // O += P V ; L += P * ones  (row-sum on the MFMA pipe)
#pragma unroll
      for (int kc = 0; kc < 4; kc++) {
        bf16x8 pf = *(const bf16x8*)&pw[l15 * PSTR + kc * 32 + quad * 8];
#pragma unroll
        for (int nt = 0; nt < 4; nt++) {
          bf16x8 vf = *(const bf16x8*)&Vts[(nt * 16 + l15) * VSTR + kc * 32 + quad * 8];
          O[g][nt] = __builtin_amdgcn_mfma_f32_16x16x32_bf16(pf, vf, O[g][nt], 0, 0, 0);
        }
        L[g] = __builtin_amdgcn_mfma_f32_16x16x32_bf16(pf, ones, L[g], 0, 0, 0);
      }
    }
  }

  // normalize + write ctx (token-major bf16). L[g][r] holds row q=quad*4+r sum (all cols equal).
#pragma unroll
  for (int g = 0; g < 2; g++) {
#pragma unroll
    for (int r = 0; r < 4; r++) {
      float inv = 1.0f / L[g][r];
      size_t row = (size_t)(b * SS) + qt * 128 + g * 64 + wave * 16 + quad * 4 + r;
#pragma unroll
      for (int nt = 0; nt < 4; nt++)
        ctx[row * HID + h * 64 + nt * 16 + l15] = f2bs(O[g][nt][r] * inv);
    }
  }
}

extern "C" void kernel_launch(void* const* d_in, const int* in_sizes, int n_in,
                              void* d_out, int out_size, void* d_ws, size_t ws_size,
                              hipStream_t stream) {
  const float* query = (const float*)d_in[0];
  const float* key_  = (const float*)d_in[1];
  const float* value = (const float*)d_in[2];
  const float* mask  = (const float*)d_in[3];
  const float* Wq = (const float*)d_in[4];
  const float* bq = (const float*)d_in[5];
  const float* Wk = (const float*)d_in[6];
  const float* bk = (const float*)d_in[7];
  const float* Wv = (const float*)d_in[8];
  const float* bv = (const float*)d_in[9];
  const float* Wo = (const float*)d_in[10];
  const float* bo = (const float*)d_in[11];
  float* out = (float*)d_out;

  const size_t ME = (size_t)MTOK * HID;
  const size_t HH = (size_t)HID * HID;
  const size_t needA = (6 * ME + 4 * HH) * 2;

  dim3 blk(256);

  if (ws_size >= needA) {
    unsigned short* xq   = (unsigned short*)d_ws;
    unsigned short* xk   = xq + ME;
    unsigned short* xv   = xk + ME;
    unsigned short* qhm  = xv + ME;   // [B,NH,S,64]
    unsigned short* khm  = qhm + ME;  // [B,NH,S,64]
    unsigned short* vth  = khm + ME;  // [B,NH,64,S]
    unsigned short* wcat = vth + ME;  // Wq,Wk,Wv bf16
    unsigned short* wobf = wcat + 3 * HH;
    unsigned short* cx   = xq;        // alias: xq dead after qkv_gemm

    cvt_all<<<3584, blk, 0, stream>>>(query, key_, value, Wq, Wk, Wv, Wo,
                                      xq, xk, xv, wcat, wobf);
    qkv_gemm<<<64 * 24, blk, 0, stream>>>(xq, xk, xv, wcat, bq, bk, bv, qhm, khm, vth);
    attn_v3<<<BB * NHEAD * (SS / 128), blk, 0, stream>>>(qhm, khm, vth, mask, cx);
    out_gemm<<<64 * 8, blk, 0, stream>>>(cx, wobf, bo, out);
  } else {
    unsigned short* qhm = (unsigned short*)d_ws;
    unsigned short* khm = qhm + ME;
    unsigned short* vth = khm + ME;
    unsigned short* cx  = vth + ME;
    const int gblocks = (MTOK / 128) * (HID / 128);  // 512

    gemm_bt<float, 1><<<gblocks, blk, 0, stream>>>(query, Wq, bq, qhm, MTOK, HID, HID);
    gemm_bt<float, 1><<<gblocks, blk, 0, stream>>>(key_, Wk, bk, khm, MTOK, HID, HID);
    gemm_bt<float, 2><<<gblocks, blk, 0, stream>>>(value, Wv, bv, vth, MTOK, HID, HID);
    attn_v3<<<BB * NHEAD * (SS / 128), blk, 0, stream>>>(qhm, khm, vth, mask, cx);
    gemm_bt<unsigned short, 0><<<gblocks, blk, 0, stream>>>(cx, Wo, bo, out, MTOK, HID, HID);
  }
}

// Round 5
// 463.873 us; speedup vs baseline: 1.0216x; 1.0216x over previous
//
#include <hip/hip_runtime.h>
#include <hip/hip_bf16.h>

#define HID 1024
#define NHEAD 16
#define HDIM 64
#define BB 4
#define SS 2048
#define MTOK (BB * SS)   // 8192 tokens

typedef __attribute__((ext_vector_type(8))) short bf16x8;
typedef __attribute__((ext_vector_type(4))) float f32x4;

__device__ __forceinline__ unsigned short f2bs(float f) {
  __hip_bfloat16 h = __float2bfloat16(f);
  unsigned short u;
  __builtin_memcpy(&u, &h, 2);
  return u;
}

// pack two fp32 -> two bf16 in one dword, round-half-up (<=0.5 ulp)
__device__ __forceinline__ unsigned int pkbf(float a, float b) {
  unsigned int ua, ub;
  __builtin_memcpy(&ua, &a, 4);
  __builtin_memcpy(&ub, &b, 4);
  return ((ua + 0x8000u) >> 16) | ((ub + 0x8000u) & 0xFFFF0000u);
}

// async global->LDS, 16B per lane. LDS dest = wave-uniform base + lane*16.
__device__ __forceinline__ void gload16(const void* g, void* l) {
  __builtin_amdgcn_global_load_lds((__attribute__((address_space(1))) const void*)g,
                                   (__attribute__((address_space(3))) void*)l, 16, 0, 0);
}

// ===================== conversion pass (fp32 -> bf16) =====================
__global__ __launch_bounds__(256) void cvt_all(
    const float* __restrict__ s_q, const float* __restrict__ s_k, const float* __restrict__ s_v,
    const float* __restrict__ wq, const float* __restrict__ wk, const float* __restrict__ wv,
    const float* __restrict__ wo,
    unsigned short* __restrict__ xq, unsigned short* __restrict__ xk, unsigned short* __restrict__ xv,
    unsigned short* __restrict__ wcat, unsigned short* __restrict__ wobf) {
  const int bid = blockIdx.x;
  const float* src;
  unsigned short* dst;
  size_t off;
  if (bid < 3072) {
    int s = bid >> 10;
    src = (s == 0 ? s_q : (s == 1 ? s_k : s_v));
    dst = (s == 0 ? xq : (s == 1 ? xk : xv));
    off = (size_t)(bid & 1023) * 8192;
  } else {
    int s = (bid - 3072) >> 7;
    src = (s == 0 ? wq : (s == 1 ? wk : (s == 2 ? wv : wo)));
    dst = (s < 3 ? wcat + (size_t)s * HID * HID : wobf);
    off = (size_t)((bid - 3072) & 127) * 8192;
  }
  src += off;
  dst += off;
  const int t = threadIdx.x;
#pragma unroll
  for (int i = 0; i < 8; i++) {
    float4 f = *(const float4*)(src + (size_t)(i * 256 + t) * 4);
    ushort4 h;
    h.x = f2bs(f.x); h.y = f2bs(f.y); h.z = f2bs(f.z); h.w = f2bs(f.w);
    *(ushort4*)(dst + (size_t)(i * 256 + t) * 4) = h;
  }
}

// ===================== fused QKV GEMM (bf16, global_load_lds) =====================
__global__ __launch_bounds__(256) void qkv_gemm(
    const unsigned short* __restrict__ xq, const unsigned short* __restrict__ xk,
    const unsigned short* __restrict__ xv, const unsigned short* __restrict__ wcat,
    const float* __restrict__ bq, const float* __restrict__ bk, const float* __restrict__ bv,
    unsigned short* __restrict__ qhm, unsigned short* __restrict__ khm,
    unsigned short* __restrict__ vth) {
  __shared__ unsigned short As[128 * 32];
  __shared__ unsigned short Bs[128 * 32];
  const int bid = blockIdx.x;
  const int mt = bid / 24, nt = bid % 24;
  const int sel = nt >> 3;
  const int m0 = mt << 7, n0 = (nt & 7) << 7;
  const int tid = threadIdx.x;
  const int lane = tid & 63, wave = tid >> 6;
  const int quad = lane >> 4, l15 = lane & 15;
  const int wm = ((wave >> 1) << 6), wn = ((wave & 1) << 6);

  const unsigned short* A = (sel == 0 ? xq : (sel == 1 ? xk : xv));
  const unsigned short* W = wcat + (size_t)sel * HID * HID;
  const float* bias = (sel == 0 ? bq : (sel == 1 ? bk : bv));

  const int c0 = wave * 128 + lane;
  const int c1 = c0 + 64;
  const unsigned short* gA0 = A + (size_t)(m0 + (c0 >> 2)) * HID + (c0 & 3) * 8;
  const unsigned short* gA1 = A + (size_t)(m0 + (c1 >> 2)) * HID + (c1 & 3) * 8;
  const unsigned short* gB0 = W + (size_t)(n0 + (c0 >> 2)) * HID + (c0 & 3) * 8;
  const unsigned short* gB1 = W + (size_t)(n0 + (c1 >> 2)) * HID + (c1 & 3) * 8;
  unsigned short* lA0 = As + (size_t)(wave * 128) * 8;
  unsigned short* lA1 = lA0 + 64 * 8;
  unsigned short* lB0 = Bs + (size_t)(wave * 128) * 8;
  unsigned short* lB1 = lB0 + 64 * 8;

  f32x4 acc[4][4] = {};

  for (int k0 = 0; k0 < HID; k0 += 32) {
    __syncthreads();
    gload16(gA0 + k0, lA0);
    gload16(gA1 + k0, lA1);
    gload16(gB0 + k0, lB0);
    gload16(gB1 + k0, lB1);
    __syncthreads();
    bf16x8 af[4], bfr[4];
#pragma unroll
    for (int i = 0; i < 4; i++)
      af[i] = *(const bf16x8*)(As + (wm + i * 16 + l15) * 32 + quad * 8);
#pragma unroll
    for (int j = 0; j < 4; j++)
      bfr[j] = *(const bf16x8*)(Bs + (wn + j * 16 + l15) * 32 + quad * 8);
#pragma unroll
    for (int i = 0; i < 4; i++)
#pragma unroll
      for (int j = 0; j < 4; j++)
        acc[i][j] = __builtin_amdgcn_mfma_f32_16x16x32_bf16(af[i], bfr[j], acc[i][j], 0, 0, 0);
  }

#pragma unroll
  for (int j = 0; j < 4; j++) {
    const int col = n0 + wn + j * 16 + l15;
    const float bvv = bias[col];
    const int hh = col >> 6, d = col & 63;
    if (sel < 2) {
      unsigned short* outp = (sel == 0 ? qhm : khm);
#pragma unroll
      for (int i = 0; i < 4; i++) {
        const int row0 = m0 + wm + i * 16 + quad * 4;
        const int bb = row0 >> 11, s0 = row0 & 2047;
        const size_t base = ((size_t)(bb * NHEAD + hh)) * SS * HDIM + (size_t)s0 * HDIM + d;
#pragma unroll
        for (int r = 0; r < 4; r++)
          outp[base + (size_t)r * HDIM] = f2bs(acc[i][j][r] + bvv);
      }
    } else {
#pragma unroll
      for (int i = 0; i < 4; i++) {
        const int row0 = m0 + wm + i * 16 + quad * 4;
        const int bb = row0 >> 11, s0 = row0 & 2047;
        ushort4 pk;
        pk.x = f2bs(acc[i][j][0] + bvv);
        pk.y = f2bs(acc[i][j][1] + bvv);
        pk.z = f2bs(acc[i][j][2] + bvv);
        pk.w = f2bs(acc[i][j][3] + bvv);
        *(ushort4*)&vth[((size_t)(bb * NHEAD + hh)) * HDIM * SS + (size_t)d * SS + s0] = pk;
      }
    }
  }
}

// ===================== out-proj GEMM (bf16 A/W, fp32 out) =====================
__global__ __launch_bounds__(256) void out_gemm(const unsigned short* __restrict__ A,
                                                const unsigned short* __restrict__ W,
                                                const float* __restrict__ bias,
                                                float* __restrict__ C) {
  __shared__ unsigned short As[128 * 32];
  __shared__ unsigned short Bs[128 * 32];
  const int bid = blockIdx.x;
  const int mt = bid >> 3, nt = bid & 7;
  const int m0 = mt << 7, n0 = nt << 7;
  const int tid = threadIdx.x;
  const int lane = tid & 63, wave = tid >> 6;
  const int quad = lane >> 4, l15 = lane & 15;
  const int wm = ((wave >> 1) << 6), wn = ((wave & 1) << 6);

  const int c0 = wave * 128 + lane;
  const int c1 = c0 + 64;
  const unsigned short* gA0 = A + (size_t)(m0 + (c0 >> 2)) * HID + (c0 & 3) * 8;
  const unsigned short* gA1 = A + (size_t)(m0 + (c1 >> 2)) * HID + (c1 & 3) * 8;
  const unsigned short* gB0 = W + (size_t)(n0 + (c0 >> 2)) * HID + (c0 & 3) * 8;
  const unsigned short* gB1 = W + (size_t)(n0 + (c1 >> 2)) * HID + (c1 & 3) * 8;
  unsigned short* lA0 = As + (size_t)(wave * 128) * 8;
  unsigned short* lA1 = lA0 + 64 * 8;
  unsigned short* lB0 = Bs + (size_t)(wave * 128) * 8;
  unsigned short* lB1 = lB0 + 64 * 8;

  f32x4 acc[4][4] = {};

  for (int k0 = 0; k0 < HID; k0 += 32) {
    __syncthreads();
    gload16(gA0 + k0, lA0);
    gload16(gA1 + k0, lA1);
    gload16(gB0 + k0, lB0);
    gload16(gB1 + k0, lB1);
    __syncthreads();
    bf16x8 af[4], bfr[4];
#pragma unroll
    for (int i = 0; i < 4; i++)
      af[i] = *(const bf16x8*)(As + (wm + i * 16 + l15) * 32 + quad * 8);
#pragma unroll
    for (int j = 0; j < 4; j++)
      bfr[j] = *(const bf16x8*)(Bs + (wn + j * 16 + l15) * 32 + quad * 8);
#pragma unroll
    for (int i = 0; i < 4; i++)
#pragma unroll
      for (int j = 0; j < 4; j++)
        acc[i][j] = __builtin_amdgcn_mfma_f32_16x16x32_bf16(af[i], bfr[j], acc[i][j], 0, 0, 0);
  }

#pragma unroll
  for (int j = 0; j < 4; j++) {
    const int col = n0 + wn + j * 16 + l15;
    const float bvv = bias[col];
#pragma unroll
    for (int i = 0; i < 4; i++) {
      const int row0 = m0 + wm + i * 16 + quad * 4;
#pragma unroll
      for (int r = 0; r < 4; r++)
        C[(size_t)(row0 + r) * HID + col] = acc[i][j][r] + bvv;
    }
  }
}

// ===================== legacy fp32-staging GEMM (fallback plan) =====================
__device__ __forceinline__ void stage_tile(unsigned short* s, const float* g, int ldg, int tid) {
#pragma unroll
  for (int i = 0; i < 4; i++) {
    int c = i * 256 + tid;
    int row = c >> 3;
    int col = (c & 7) * 4;
    const float4 v = *(const float4*)(g + (size_t)row * ldg + col);
    ushort4 hv;
    hv.x = f2bs(v.x); hv.y = f2bs(v.y); hv.z = f2bs(v.z); hv.w = f2bs(v.w);
    *(ushort4*)(s + c * 4) = hv;
  }
}
__device__ __forceinline__ void stage_tile(unsigned short* s, const unsigned short* g, int ldg, int tid) {
#pragma unroll
  for (int i = 0; i < 2; i++) {
    int c = i * 256 + tid;
    int row = c >> 2;
    int col = (c & 3) * 8;
    const uint4 v = *(const uint4*)(g + (size_t)row * ldg + col);
    *(uint4*)(s + c * 8) = v;
  }
}

template <typename TA, int MODE>
__global__ __launch_bounds__(256) void gemm_bt(const TA* __restrict__ A, const float* __restrict__ W,
                                               const float* __restrict__ bias, void* __restrict__ Cp,
                                               int M, int N, int K) {
  __shared__ unsigned short As[128 * 32];
  __shared__ unsigned short Bs[128 * 32];
  const int nb = N >> 7;
  const int m0 = (blockIdx.x / nb) << 7;
  const int n0 = (blockIdx.x % nb) << 7;
  const int tid = threadIdx.x;
  const int lane = tid & 63, wave = tid >> 6;
  const int quad = lane >> 4, l15 = lane & 15;
  const int wm = ((wave >> 1) << 6), wn = ((wave & 1) << 6);

  f32x4 acc[4][4] = {};

  for (int k0 = 0; k0 < K; k0 += 32) {
    __syncthreads();
    stage_tile(As, A + (size_t)m0 * K + k0, K, tid);
    stage_tile(Bs, W + (size_t)n0 * K + k0, K, tid);
    __syncthreads();
    bf16x8 af[4], bfr[4];
#pragma unroll
    for (int i = 0; i < 4; i++)
      af[i] = *(const bf16x8*)(As + (wm + i * 16 + l15) * 32 + quad * 8);
#pragma unroll
    for (int j = 0; j < 4; j++)
      bfr[j] = *(const bf16x8*)(Bs + (wn + j * 16 + l15) * 32 + quad * 8);
#pragma unroll
    for (int i = 0; i < 4; i++)
#pragma unroll
      for (int j = 0; j < 4; j++)
        acc[i][j] = __builtin_amdgcn_mfma_f32_16x16x32_bf16(af[i], bfr[j], acc[i][j], 0, 0, 0);
  }

#pragma unroll
  for (int j = 0; j < 4; j++) {
    const int col = n0 + wn + j * 16 + l15;
    const float bvv = bias[col];
    if constexpr (MODE == 0) {
      float* outp = (float*)Cp;
#pragma unroll
      for (int i = 0; i < 4; i++) {
        const int row0 = m0 + wm + i * 16 + quad * 4;
#pragma unroll
        for (int r = 0; r < 4; r++)
          outp[(size_t)(row0 + r) * N + col] = acc[i][j][r] + bvv;
      }
    } else if constexpr (MODE == 1) {
      unsigned short* outp = (unsigned short*)Cp;
      const int hh = col >> 6, d = col & 63;
#pragma unroll
      for (int i = 0; i < 4; i++) {
        const int row0 = m0 + wm + i * 16 + quad * 4;
        const int bb = row0 >> 11, s0 = row0 & 2047;
        const size_t base = ((size_t)(bb * NHEAD + hh)) * SS * HDIM + (size_t)s0 * HDIM + d;
#pragma unroll
        for (int r = 0; r < 4; r++)
          outp[base + (size_t)r * HDIM] = f2bs(acc[i][j][r] + bvv);
      }
    } else {
      unsigned short* outp = (unsigned short*)Cp;
      const int hh = col >> 6, d = col & 63;
#pragma unroll
      for (int i = 0; i < 4; i++) {
        const int row0 = m0 + wm + i * 16 + quad * 4;
        const int bb = row0 >> 11, s0 = row0 & 2047;
        ushort4 pk;
        pk.x = f2bs(acc[i][j][0] + bvv);
        pk.y = f2bs(acc[i][j][1] + bvv);
        pk.z = f2bs(acc[i][j][2] + bvv);
        pk.w = f2bs(acc[i][j][3] + bvv);
        *(ushort4*)&outp[((size_t)(bb * NHEAD + hh)) * HDIM * SS + (size_t)d * SS + s0] = pk;
      }
    }
  }
}

// ===================== flash attention v4 =====================
// 1024 blocks = (qt-major: bid = qt*64 + b*16 + h) so all 16 q-tiles of a
// (b,h) land on one XCD (bid&7 == bh&7). 4 waves x 2 sequential 16-row groups.
// Inline K/V staging (short-lived regs, no spill — round-4 lesson);
// constant-shift softmax; row-sum via ones-fragment MFMA.
#define KSTR 72
#define VSTR 136
#define PSTR 136

__global__ __launch_bounds__(256) void attn_v4(const unsigned short* __restrict__ q,
                                               const unsigned short* __restrict__ k,
                                               const unsigned short* __restrict__ vt,
                                               const float* __restrict__ mask,
                                               unsigned short* __restrict__ ctx) {
  __shared__ unsigned short Ks[128 * KSTR];
  __shared__ unsigned short Vts[64 * VSTR];
  __shared__ unsigned short Ps[4 * 16 * PSTR];
  __shared__ float Ms[128];

  const int bid = blockIdx.x;
  const int qt = bid >> 6;            // 16 q tiles, major
  const int bh = bid & 63;
  const int b  = bh >> 4;
  const int h  = bh & 15;
  const int tid = threadIdx.x;
  const int wave = tid >> 6, lane = tid & 63;
  const int quad = lane >> 4, l15 = lane & 15;

  // Q fragments for both 16-row groups (B operand of S^T = K Q^T)
  bf16x8 qf[2][2];
#pragma unroll
  for (int g = 0; g < 2; g++) {
    const unsigned short* qb =
        q + ((size_t)bh * SS + qt * 128 + g * 64 + wave * 16 + l15) * HDIM;
    qf[g][0] = *(const bf16x8*)(qb + quad * 8);
    qf[g][1] = *(const bf16x8*)(qb + 32 + quad * 8);
  }

  f32x4 O[2][4] = {};
  f32x4 L[2] = {};

  bf16x8 ones;
#pragma unroll
  for (int i = 0; i < 8; i++) ones[i] = (short)0x3F80;   // bf16 1.0

  const unsigned short* kg0 = k + (size_t)bh * SS * HDIM;
  const unsigned short* vg0 = vt + (size_t)bh * HDIM * SS;
  unsigned short* pw = &Ps[wave * 16 * PSTR];

  for (int kb = 0; kb < SS / 128; kb++) {
    // load this tile into short-lived regs (issued before barrier so the
    // latency overlaps the barrier wait; regs die at the ds_writes below)
    const unsigned short* kg = kg0 + (size_t)kb * 128 * HDIM;
    const unsigned short* vg = vg0 + (size_t)kb * 128;
    uint4 kt[4], vt4[4];
#pragma unroll
    for (int i = 0; i < 4; i++) {
      int c = i * 256 + tid;
      kt[i] = *(const uint4*)(kg + c * 8);
      int row = c >> 4, col = (c & 15) * 8;
      vt4[i] = *(const uint4*)(vg + (size_t)row * SS + col);
    }
    float mreg = 0.0f;
    if (tid < 128) mreg = mask[(size_t)b * SS + kb * 128 + tid];

    __syncthreads();  // all waves done reading previous Ks/Vts
#pragma unroll
    for (int i = 0; i < 4; i++) {
      int c = i * 256 + tid;
      int row = c >> 3, col = (c & 7) * 8;
      *(uint4*)&Ks[row * KSTR + col] = kt[i];
    }
#pragma unroll
    for (int i = 0; i < 4; i++) {
      int c = i * 256 + tid;
      int row = c >> 4, col = (c & 15) * 8;
      *(uint4*)&Vts[row * VSTR + col] = vt4[i];
    }
    if (tid < 128) Ms[tid] = (1.0f - mreg) * -10000.0f - 8.0f;  // mask + const shift
    __syncthreads();

#pragma unroll
    for (int g = 0; g < 2; g++) {
      // S^T = K Q^T : col=l15 (q), row=quad*4+r (kv within mt)
      f32x4 Sc[8];
#pragma unroll
      for (int mt = 0; mt < 8; mt++) {
        f32x4 z = {};
#pragma unroll
        for (int kc = 0; kc < 2; kc++) {
          bf16x8 kf = *(const bf16x8*)&Ks[(mt * 16 + l15) * KSTR + kc * 32 + quad * 8];
          z = __builtin_amdgcn_mfma_f32_16x16x32_bf16(kf, qf[g][kc], z, 0, 0, 0);
        }
        f32x4 mv = *(const f32x4*)&Ms[mt * 16 + quad * 4];
        Sc[mt] = z * 0.125f + mv;
      }
      // exp (constant shift already applied via Ms; exact softmax value)
#pragma unroll
      for (int mt = 0; mt < 8; mt++)
#pragma unroll
        for (int r = 0; r < 4; r++) Sc[mt][r] = __expf(Sc[mt][r]);

      // P -> LDS (per-wave region, contiguous dword pairs)
#pragma unroll
      for (int mt = 0; mt < 8; mt++) {
        uint2 u;
        u.x = pkbf(Sc[mt][0], Sc[mt][1]);
        u.y = pkbf(Sc[mt][2], Sc[mt][3]);
        *(uint2*)&pw[l15 * PSTR + mt * 16 + quad * 4] = u;
      }

      // O += P V ; L += P * ones  (row-sum on the MFMA pipe)
#pragma unroll
      for (int kc = 0; kc < 4; kc++) {
        bf16x8 pf = *(const bf16x8*)&pw[l15 * PSTR + kc * 32 + quad * 8];
#pragma unroll
        for (int nt = 0; nt < 4; nt++) {
          bf16x8 vf = *(const bf16x8*)&Vts[(nt * 16 + l15) * VSTR + kc * 32 + quad * 8];
          O[g][nt] = __builtin_amdgcn_mfma_f32_16x16x32_bf16(pf, vf, O[g][nt], 0, 0, 0);
        }
        L[g] = __builtin_amdgcn_mfma_f32_16x16x32_bf16(pf, ones, L[g], 0, 0, 0);
      }
    }
  }

  // normalize + write ctx (token-major bf16). L[g][r] = row sum (all cols equal).
#pragma unroll
  for (int g = 0; g < 2; g++) {
#pragma unroll
    for (int r = 0; r < 4; r++) {
      float inv = 1.0f / L[g][r];
      size_t row = (size_t)(b * SS) + qt * 128 + g * 64 + wave * 16 + quad * 4 + r;
#pragma unroll
      for (int nt = 0; nt < 4; nt++)
        ctx[row * HID + h * 64 + nt * 16 + l15] = f2bs(O[g][nt][r] * inv);
    }
  }
}

extern "C" void kernel_launch(void* const* d_in, const int* in_sizes, int n_in,
                              void* d_out, int out_size, void* d_ws, size_t ws_size,
                              hipStream_t stream) {
  const float* query = (const float*)d_in[0];
  const float* key_  = (const float*)d_in[1];
  const float* value = (const float*)d_in[2];
  const float* mask  = (const float*)d_in[3];
  const float* Wq = (const float*)d_in[4];
  const float* bq = (const float*)d_in[5];
  const float* Wk = (const float*)d_in[6];
  const float* bk = (const float*)d_in[7];
  const float* Wv = (const float*)d_in[8];
  const float* bv = (const float*)d_in[9];
  const float* Wo = (const float*)d_in[10];
  const float* bo = (const float*)d_in[11];
  float* out = (float*)d_out;

  const size_t ME = (size_t)MTOK * HID;
  const size_t HH = (size_t)HID * HID;
  const size_t needA = (6 * ME + 4 * HH) * 2;

  dim3 blk(256);

  if (ws_size >= needA) {
    unsigned short* xq   = (unsigned short*)d_ws;
    unsigned short* xk   = xq + ME;
    unsigned short* xv   = xk + ME;
    unsigned short* qhm  = xv + ME;   // [B,NH,S,64]
    unsigned short* khm  = qhm + ME;  // [B,NH,S,64]
    unsigned short* vth  = khm + ME;  // [B,NH,64,S]
    unsigned short* wcat = vth + ME;  // Wq,Wk,Wv bf16
    unsigned short* wobf = wcat + 3 * HH;
    unsigned short* cx   = xq;        // alias: xq dead after qkv_gemm

    cvt_all<<<3584, blk, 0, stream>>>(query, key_, value, Wq, Wk, Wv, Wo,
                                      xq, xk, xv, wcat, wobf);
    qkv_gemm<<<64 * 24, blk, 0, stream>>>(xq, xk, xv, wcat, bq, bk, bv, qhm, khm, vth);
    attn_v4<<<BB * NHEAD * (SS / 128), blk, 0, stream>>>(qhm, khm, vth, mask, cx);
    out_gemm<<<64 * 8, blk, 0, stream>>>(cx, wobf, bo, out);
  } else {
    unsigned short* qhm = (unsigned short*)d_ws;
    unsigned short* khm = qhm + ME;
    unsigned short* vth = khm + ME;
    unsigned short* cx  = vth + ME;
    const int gblocks = (MTOK / 128) * (HID / 128);  // 512

    gemm_bt<float, 1><<<gblocks, blk, 0, stream>>>(query, Wq, bq, qhm, MTOK, HID, HID);
    gemm_bt<float, 1><<<gblocks, blk, 0, stream>>>(key_, Wk, bk, khm, MTOK, HID, HID);
    gemm_bt<float, 2><<<gblocks, blk, 0, stream>>>(value, Wv, bv, vth, MTOK, HID, HID);
    attn_v4<<<BB * NHEAD * (SS / 128), blk, 0, stream>>>(qhm, khm, vth, mask, cx);
    gemm_bt<unsigned short, 0><<<gblocks, blk, 0, stream>>>(cx, Wo, bo, out, MTOK, HID, HID);
  }
}

// Round 6
// 396.149 us; speedup vs baseline: 1.1962x; 1.1710x over previous
//
#include <hip/hip_runtime.h>
#include <hip/hip_bf16.h>

#define HID 1024
#define NHEAD 16
#define HDIM 64
#define BB 4
#define SS 2048
#define MTOK (BB * SS)   // 8192 tokens

typedef __attribute__((ext_vector_type(8))) short bf16x8;
typedef __attribute__((ext_vector_type(4))) float f32x4;

__device__ __forceinline__ unsigned short f2bs(float f) {
  __hip_bfloat16 h = __float2bfloat16(f);
  unsigned short u;
  __builtin_memcpy(&u, &h, 2);
  return u;
}

// pack two fp32 -> two bf16 in one dword, round-half-up (<=0.5 ulp)
__device__ __forceinline__ unsigned int pkbf(float a, float b) {
  unsigned int ua, ub;
  __builtin_memcpy(&ua, &a, 4);
  __builtin_memcpy(&ub, &b, 4);
  return ((ua + 0x8000u) >> 16) | ((ub + 0x8000u) & 0xFFFF0000u);
}

// async global->LDS, 16B per lane. LDS dest = wave-uniform base + lane*16.
__device__ __forceinline__ void gload16(const void* g, void* l) {
  __builtin_amdgcn_global_load_lds((__attribute__((address_space(1))) const void*)g,
                                   (__attribute__((address_space(3))) void*)l, 16, 0, 0);
}

// ===================== conversion pass (fp32 -> bf16) =====================
__global__ __launch_bounds__(256) void cvt_all(
    const float* __restrict__ s_q, const float* __restrict__ s_k, const float* __restrict__ s_v,
    const float* __restrict__ wq, const float* __restrict__ wk, const float* __restrict__ wv,
    const float* __restrict__ wo,
    unsigned short* __restrict__ xq, unsigned short* __restrict__ xk, unsigned short* __restrict__ xv,
    unsigned short* __restrict__ wcat, unsigned short* __restrict__ wobf) {
  const int bid = blockIdx.x;
  const float* src;
  unsigned short* dst;
  size_t off;
  if (bid < 3072) {
    int s = bid >> 10;
    src = (s == 0 ? s_q : (s == 1 ? s_k : s_v));
    dst = (s == 0 ? xq : (s == 1 ? xk : xv));
    off = (size_t)(bid & 1023) * 8192;
  } else {
    int s = (bid - 3072) >> 7;
    src = (s == 0 ? wq : (s == 1 ? wk : (s == 2 ? wv : wo)));
    dst = (s < 3 ? wcat + (size_t)s * HID * HID : wobf);
    off = (size_t)((bid - 3072) & 127) * 8192;
  }
  src += off;
  dst += off;
  const int t = threadIdx.x;
#pragma unroll
  for (int i = 0; i < 8; i++) {
    float4 f = *(const float4*)(src + (size_t)(i * 256 + t) * 4);
    ushort4 h;
    h.x = f2bs(f.x); h.y = f2bs(f.y); h.z = f2bs(f.z); h.w = f2bs(f.w);
    *(ushort4*)(dst + (size_t)(i * 256 + t) * 4) = h;
  }
}

// ===================== fused QKV GEMM (bf16, global_load_lds) =====================
__global__ __launch_bounds__(256) void qkv_gemm(
    const unsigned short* __restrict__ xq, const unsigned short* __restrict__ xk,
    const unsigned short* __restrict__ xv, const unsigned short* __restrict__ wcat,
    const float* __restrict__ bq, const float* __restrict__ bk, const float* __restrict__ bv,
    unsigned short* __restrict__ qhm, unsigned short* __restrict__ khm,
    unsigned short* __restrict__ vth) {
  __shared__ unsigned short As[128 * 32];
  __shared__ unsigned short Bs[128 * 32];
  const int bid = blockIdx.x;
  const int mt = bid / 24, nt = bid % 24;
  const int sel = nt >> 3;
  const int m0 = mt << 7, n0 = (nt & 7) << 7;
  const int tid = threadIdx.x;
  const int lane = tid & 63, wave = tid >> 6;
  const int quad = lane >> 4, l15 = lane & 15;
  const int wm = ((wave >> 1) << 6), wn = ((wave & 1) << 6);

  const unsigned short* A = (sel == 0 ? xq : (sel == 1 ? xk : xv));
  const unsigned short* W = wcat + (size_t)sel * HID * HID;
  const float* bias = (sel == 0 ? bq : (sel == 1 ? bk : bv));

  const int c0 = wave * 128 + lane;
  const int c1 = c0 + 64;
  const unsigned short* gA0 = A + (size_t)(m0 + (c0 >> 2)) * HID + (c0 & 3) * 8;
  const unsigned short* gA1 = A + (size_t)(m0 + (c1 >> 2)) * HID + (c1 & 3) * 8;
  const unsigned short* gB0 = W + (size_t)(n0 + (c0 >> 2)) * HID + (c0 & 3) * 8;
  const unsigned short* gB1 = W + (size_t)(n0 + (c1 >> 2)) * HID + (c1 & 3) * 8;
  unsigned short* lA0 = As + (size_t)(wave * 128) * 8;
  unsigned short* lA1 = lA0 + 64 * 8;
  unsigned short* lB0 = Bs + (size_t)(wave * 128) * 8;
  unsigned short* lB1 = lB0 + 64 * 8;

  f32x4 acc[4][4] = {};

  for (int k0 = 0; k0 < HID; k0 += 32) {
    __syncthreads();
    gload16(gA0 + k0, lA0);
    gload16(gA1 + k0, lA1);
    gload16(gB0 + k0, lB0);
    gload16(gB1 + k0, lB1);
    __syncthreads();
    bf16x8 af[4], bfr[4];
#pragma unroll
    for (int i = 0; i < 4; i++)
      af[i] = *(const bf16x8*)(As + (wm + i * 16 + l15) * 32 + quad * 8);
#pragma unroll
    for (int j = 0; j < 4; j++)
      bfr[j] = *(const bf16x8*)(Bs + (wn + j * 16 + l15) * 32 + quad * 8);
#pragma unroll
    for (int i = 0; i < 4; i++)
#pragma unroll
      for (int j = 0; j < 4; j++)
        acc[i][j] = __builtin_amdgcn_mfma_f32_16x16x32_bf16(af[i], bfr[j], acc[i][j], 0, 0, 0);
  }

#pragma unroll
  for (int j = 0; j < 4; j++) {
    const int col = n0 + wn + j * 16 + l15;
    const float bvv = bias[col];
    const int hh = col >> 6, d = col & 63;
    if (sel < 2) {
      unsigned short* outp = (sel == 0 ? qhm : khm);
#pragma unroll
      for (int i = 0; i < 4; i++) {
        const int row0 = m0 + wm + i * 16 + quad * 4;
        const int bb = row0 >> 11, s0 = row0 & 2047;
        const size_t base = ((size_t)(bb * NHEAD + hh)) * SS * HDIM + (size_t)s0 * HDIM + d;
#pragma unroll
        for (int r = 0; r < 4; r++)
          outp[base + (size_t)r * HDIM] = f2bs(acc[i][j][r] + bvv);
      }
    } else {
#pragma unroll
      for (int i = 0; i < 4; i++) {
        const int row0 = m0 + wm + i * 16 + quad * 4;
        const int bb = row0 >> 11, s0 = row0 & 2047;
        ushort4 pk;
        pk.x = f2bs(acc[i][j][0] + bvv);
        pk.y = f2bs(acc[i][j][1] + bvv);
        pk.z = f2bs(acc[i][j][2] + bvv);
        pk.w = f2bs(acc[i][j][3] + bvv);
        *(ushort4*)&vth[((size_t)(bb * NHEAD + hh)) * HDIM * SS + (size_t)d * SS + s0] = pk;
      }
    }
  }
}

// ===================== out-proj GEMM (bf16 A/W, fp32 out) =====================
__global__ __launch_bounds__(256) void out_gemm(const unsigned short* __restrict__ A,
                                                const unsigned short* __restrict__ W,
                                                const float* __restrict__ bias,
                                                float* __restrict__ C) {
  __shared__ unsigned short As[128 * 32];
  __shared__ unsigned short Bs[128 * 32];
  const int bid = blockIdx.x;
  const int mt = bid >> 3, nt = bid & 7;
  const int m0 = mt << 7, n0 = nt << 7;
  const int tid = threadIdx.x;
  const int lane = tid & 63, wave = tid >> 6;
  const int quad = lane >> 4, l15 = lane & 15;
  const int wm = ((wave >> 1) << 6), wn = ((wave & 1) << 6);

  const int c0 = wave * 128 + lane;
  const int c1 = c0 + 64;
  const unsigned short* gA0 = A + (size_t)(m0 + (c0 >> 2)) * HID + (c0 & 3) * 8;
  const unsigned short* gA1 = A + (size_t)(m0 + (c1 >> 2)) * HID + (c1 & 3) * 8;
  const unsigned short* gB0 = W + (size_t)(n0 + (c0 >> 2)) * HID + (c0 & 3) * 8;
  const unsigned short* gB1 = W + (size_t)(n0 + (c1 >> 2)) * HID + (c1 & 3) * 8;
  unsigned short* lA0 = As + (size_t)(wave * 128) * 8;
  unsigned short* lA1 = lA0 + 64 * 8;
  unsigned short* lB0 = Bs + (size_t)(wave * 128) * 8;
  unsigned short* lB1 = lB0 + 64 * 8;

  f32x4 acc[4][4] = {};

  for (int k0 = 0; k0 < HID; k0 += 32) {
    __syncthreads();
    gload16(gA0 + k0, lA0);
    gload16(gA1 + k0, lA1);
    gload16(gB0 + k0, lB0);
    gload16(gB1 + k0, lB1);
    __syncthreads();
    bf16x8 af[4], bfr[4];
#pragma unroll
    for (int i = 0; i < 4; i++)
      af[i] = *(const bf16x8*)(As + (wm + i * 16 + l15) * 32 + quad * 8);
#pragma unroll
    for (int j = 0; j < 4; j++)
      bfr[j] = *(const bf16x8*)(Bs + (wn + j * 16 + l15) * 32 + quad * 8);
#pragma unroll
    for (int i = 0; i < 4; i++)
#pragma unroll
      for (int j = 0; j < 4; j++)
        acc[i][j] = __builtin_amdgcn_mfma_f32_16x16x32_bf16(af[i], bfr[j], acc[i][j], 0, 0, 0);
  }

#pragma unroll
  for (int j = 0; j < 4; j++) {
    const int col = n0 + wn + j * 16 + l15;
    const float bvv = bias[col];
#pragma unroll
    for (int i = 0; i < 4; i++) {
      const int row0 = m0 + wm + i * 16 + quad * 4;
#pragma unroll
      for (int r = 0; r < 4; r++)
        C[(size_t)(row0 + r) * HID + col] = acc[i][j][r] + bvv;
    }
  }
}

// ===================== legacy fp32-staging GEMM (fallback plan) =====================
__device__ __forceinline__ void stage_tile(unsigned short* s, const float* g, int ldg, int tid) {
#pragma unroll
  for (int i = 0; i < 4; i++) {
    int c = i * 256 + tid;
    int row = c >> 3;
    int col = (c & 7) * 4;
    const float4 v = *(const float4*)(g + (size_t)row * ldg + col);
    ushort4 hv;
    hv.x = f2bs(v.x); hv.y = f2bs(v.y); hv.z = f2bs(v.z); hv.w = f2bs(v.w);
    *(ushort4*)(s + c * 4) = hv;
  }
}
__device__ __forceinline__ void stage_tile(unsigned short* s, const unsigned short* g, int ldg, int tid) {
#pragma unroll
  for (int i = 0; i < 2; i++) {
    int c = i * 256 + tid;
    int row = c >> 2;
    int col = (c & 3) * 8;
    const uint4 v = *(const uint4*)(g + (size_t)row * ldg + col);
    *(uint4*)(s + c * 8) = v;
  }
}

template <typename TA, int MODE>
__global__ __launch_bounds__(256) void gemm_bt(const TA* __restrict__ A, const float* __restrict__ W,
                                               const float* __restrict__ bias, void* __restrict__ Cp,
                                               int M, int N, int K) {
  __shared__ unsigned short As[128 * 32];
  __shared__ unsigned short Bs[128 * 32];
  const int nb = N >> 7;
  const int m0 = (blockIdx.x / nb) << 7;
  const int n0 = (blockIdx.x % nb) << 7;
  const int tid = threadIdx.x;
  const int lane = tid & 63, wave = tid >> 6;
  const int quad = lane >> 4, l15 = lane & 15;
  const int wm = ((wave >> 1) << 6), wn = ((wave & 1) << 6);

  f32x4 acc[4][4] = {};

  for (int k0 = 0; k0 < K; k0 += 32) {
    __syncthreads();
    stage_tile(As, A + (size_t)m0 * K + k0, K, tid);
    stage_tile(Bs, W + (size_t)n0 * K + k0, K, tid);
    __syncthreads();
    bf16x8 af[4], bfr[4];
#pragma unroll
    for (int i = 0; i < 4; i++)
      af[i] = *(const bf16x8*)(As + (wm + i * 16 + l15) * 32 + quad * 8);
#pragma unroll
    for (int j = 0; j < 4; j++)
      bfr[j] = *(const bf16x8*)(Bs + (wn + j * 16 + l15) * 32 + quad * 8);
#pragma unroll
    for (int i = 0; i < 4; i++)
#pragma unroll
      for (int j = 0; j < 4; j++)
        acc[i][j] = __builtin_amdgcn_mfma_f32_16x16x32_bf16(af[i], bfr[j], acc[i][j], 0, 0, 0);
  }

#pragma unroll
  for (int j = 0; j < 4; j++) {
    const int col = n0 + wn + j * 16 + l15;
    const float bvv = bias[col];
    if constexpr (MODE == 0) {
      float* outp = (float*)Cp;
#pragma unroll
      for (int i = 0; i < 4; i++) {
        const int row0 = m0 + wm + i * 16 + quad * 4;
#pragma unroll
        for (int r = 0; r < 4; r++)
          outp[(size_t)(row0 + r) * N + col] = acc[i][j][r] + bvv;
      }
    } else if constexpr (MODE == 1) {
      unsigned short* outp = (unsigned short*)Cp;
      const int hh = col >> 6, d = col & 63;
#pragma unroll
      for (int i = 0; i < 4; i++) {
        const int row0 = m0 + wm + i * 16 + quad * 4;
        const int bb = row0 >> 11, s0 = row0 & 2047;
        const size_t base = ((size_t)(bb * NHEAD + hh)) * SS * HDIM + (size_t)s0 * HDIM + d;
#pragma unroll
        for (int r = 0; r < 4; r++)
          outp[base + (size_t)r * HDIM] = f2bs(acc[i][j][r] + bvv);
      }
    } else {
      unsigned short* outp = (unsigned short*)Cp;
      const int hh = col >> 6, d = col & 63;
#pragma unroll
      for (int i = 0; i < 4; i++) {
        const int row0 = m0 + wm + i * 16 + quad * 4;
        const int bb = row0 >> 11, s0 = row0 & 2047;
        ushort4 pk;
        pk.x = f2bs(acc[i][j][0] + bvv);
        pk.y = f2bs(acc[i][j][1] + bvv);
        pk.z = f2bs(acc[i][j][2] + bvv);
        pk.w = f2bs(acc[i][j][3] + bvv);
        *(ushort4*)&outp[((size_t)(bb * NHEAD + hh)) * HDIM * SS + (size_t)d * SS + s0] = pk;
      }
    }
  }
}

// ===================== flash attention v5 =====================
// 1024 blocks x 512 threads. bid = qt*64 + b*16 + h (16 q-tiles of a (b,h)
// share an XCD). 8 waves; each wave owns ONE 16-row q group — per-thread
// persistent regs back to the proven no-spill level (round-5 lesson: the
// 2-group design's doubled accumulators caused 450 MB of scratch spill).
// v2-style inline staging (load -> immediate ds_write, no cross-barrier
// live ranges); const-shift softmax; ones-fragment MFMA row-sum.
#define KSTR 72
#define VSTR 136
#define PSTR 136

__global__ __launch_bounds__(512) void attn_v5(const unsigned short* __restrict__ q,
                                               const unsigned short* __restrict__ k,
                                               const unsigned short* __restrict__ vt,
                                               const float* __restrict__ mask,
                                               unsigned short* __restrict__ ctx) {
  __shared__ unsigned short Ks[128 * KSTR];       // 18.0 KB
  __shared__ unsigned short Vts[64 * VSTR];       // 17.0 KB
  __shared__ unsigned short Ps[8 * 16 * PSTR];    // 34.0 KB
  __shared__ float Ms[128];

  const int bid = blockIdx.x;
  const int qt = bid >> 6;            // 16 q tiles, major
  const int bh = bid & 63;
  const int b  = bh >> 4;
  const int h  = bh & 15;
  const int tid = threadIdx.x;
  const int wave = tid >> 6, lane = tid & 63;
  const int quad = lane >> 4, l15 = lane & 15;
  const int q0 = qt * 128 + wave * 16;

  // Q fragments (B operand of S^T = K Q^T)
  const unsigned short* qb = q + ((size_t)bh * SS + q0 + l15) * HDIM;
  bf16x8 qf[2];
  qf[0] = *(const bf16x8*)(qb + quad * 8);
  qf[1] = *(const bf16x8*)(qb + 32 + quad * 8);

  f32x4 O[4] = {};
  f32x4 L = {};

  bf16x8 ones;
#pragma unroll
  for (int i = 0; i < 8; i++) ones[i] = (short)0x3F80;   // bf16 1.0

  const unsigned short* kg0 = k + (size_t)bh * SS * HDIM;
  const unsigned short* vg0 = vt + (size_t)bh * HDIM * SS;
  unsigned short* pw = &Ps[wave * 16 * PSTR];

  for (int kb = 0; kb < SS / 128; kb++) {
    __syncthreads();  // all waves done reading previous Ks/Vts
    {
      const unsigned short* kg = kg0 + (size_t)kb * 128 * HDIM;
      const unsigned short* vg = vg0 + (size_t)kb * 128;
      // K tile: 1024 chunks of 8 elems over 512 threads
#pragma unroll
      for (int i = 0; i < 2; i++) {
        int c = i * 512 + tid;
        uint4 kv4 = *(const uint4*)(kg + c * 8);
        int row = c >> 3, col = (c & 7) * 8;
        *(uint4*)&Ks[row * KSTR + col] = kv4;
      }
      // Vt tile: 64 d-rows x 128 kv (global row stride SS)
#pragma unroll
      for (int i = 0; i < 2; i++) {
        int c = i * 512 + tid;
        int row = c >> 4, col = (c & 15) * 8;
        uint4 vv = *(const uint4*)(vg + (size_t)row * SS + col);
        *(uint4*)&Vts[row * VSTR + col] = vv;
      }
      if (tid < 128)
        Ms[tid] = (1.0f - mask[(size_t)b * SS + kb * 128 + tid]) * -10000.0f - 8.0f;
    }
    __syncthreads();

    // S^T = K Q^T : col=l15 (q), row=quad*4+r (kv within mt)
    f32x4 Sc[8];
#pragma unroll
    for (int mt = 0; mt < 8; mt++) {
      f32x4 z = {};
#pragma unroll
      for (int kc = 0; kc < 2; kc++) {
        bf16x8 kf = *(const bf16x8*)&Ks[(mt * 16 + l15) * KSTR + kc * 32 + quad * 8];
        z = __builtin_amdgcn_mfma_f32_16x16x32_bf16(kf, qf[kc], z, 0, 0, 0);
      }
      f32x4 mv = *(const f32x4*)&Ms[mt * 16 + quad * 4];
      Sc[mt] = z * 0.125f + mv;
    }
    // exp (constant shift applied via Ms; exact softmax value after normalize)
#pragma unroll
    for (int mt = 0; mt < 8; mt++)
#pragma unroll
      for (int r = 0; r < 4; r++) Sc[mt][r] = __expf(Sc[mt][r]);

    // P -> LDS (per-wave region, contiguous dword pairs)
#pragma unroll
    for (int mt = 0; mt < 8; mt++) {
      uint2 u;
      u.x = pkbf(Sc[mt][0], Sc[mt][1]);
      u.y = pkbf(Sc[mt][2], Sc[mt][3]);
      *(uint2*)&pw[l15 * PSTR + mt * 16 + quad * 4] = u;
    }

    // O += P V ; L += P * ones  (row-sum on the MFMA pipe)
#pragma unroll
    for (int kc = 0; kc < 4; kc++) {
      bf16x8 pf = *(const bf16x8*)&pw[l15 * PSTR + kc * 32 + quad * 8];
#pragma unroll
      for (int nt = 0; nt < 4; nt++) {
        bf16x8 vf = *(const bf16x8*)&Vts[(nt * 16 + l15) * VSTR + kc * 32 + quad * 8];
        O[nt] = __builtin_amdgcn_mfma_f32_16x16x32_bf16(pf, vf, O[nt], 0, 0, 0);
      }
      L = __builtin_amdgcn_mfma_f32_16x16x32_bf16(pf, ones, L, 0, 0, 0);
    }
  }

  // normalize + write ctx (token-major bf16). L[r] = row sum (all cols equal).
#pragma unroll
  for (int r = 0; r < 4; r++) {
    float inv = 1.0f / L[r];
    size_t row = (size_t)(b * SS) + q0 + quad * 4 + r;
#pragma unroll
    for (int nt = 0; nt < 4; nt++)
      ctx[row * HID + h * 64 + nt * 16 + l15] = f2bs(O[nt][r] * inv);
  }
}

extern "C" void kernel_launch(void* const* d_in, const int* in_sizes, int n_in,
                              void* d_out, int out_size, void* d_ws, size_t ws_size,
                              hipStream_t stream) {
  const float* query = (const float*)d_in[0];
  const float* key_  = (const float*)d_in[1];
  const float* value = (const float*)d_in[2];
  const float* mask  = (const float*)d_in[3];
  const float* Wq = (const float*)d_in[4];
  const float* bq = (const float*)d_in[5];
  const float* Wk = (const float*)d_in[6];
  const float* bk = (const float*)d_in[7];
  const float* Wv = (const float*)d_in[8];
  const float* bv = (const float*)d_in[9];
  const float* Wo = (const float*)d_in[10];
  const float* bo = (const float*)d_in[11];
  float* out = (float*)d_out;

  const size_t ME = (size_t)MTOK * HID;
  const size_t HH = (size_t)HID * HID;
  const size_t needA = (6 * ME + 4 * HH) * 2;

  dim3 blk(256);
  dim3 blk512(512);

  if (ws_size >= needA) {
    unsigned short* xq   = (unsigned short*)d_ws;
    unsigned short* xk   = xq + ME;
    unsigned short* xv   = xk + ME;
    unsigned short* qhm  = xv + ME;   // [B,NH,S,64]
    unsigned short* khm  = qhm + ME;  // [B,NH,S,64]
    unsigned short* vth  = khm + ME;  // [B,NH,64,S]
    unsigned short* wcat = vth + ME;  // Wq,Wk,Wv bf16
    unsigned short* wobf = wcat + 3 * HH;
    unsigned short* cx   = xq;        // alias: xq dead after qkv_gemm

    cvt_all<<<3584, blk, 0, stream>>>(query, key_, value, Wq, Wk, Wv, Wo,
                                      xq, xk, xv, wcat, wobf);
    qkv_gemm<<<64 * 24, blk, 0, stream>>>(xq, xk, xv, wcat, bq, bk, bv, qhm, khm, vth);
    attn_v5<<<BB * NHEAD * (SS / 128), blk512, 0, stream>>>(qhm, khm, vth, mask, cx);
    out_gemm<<<64 * 8, blk, 0, stream>>>(cx, wobf, bo, out);
  } else {
    unsigned short* qhm = (unsigned short*)d_ws;
    unsigned short* khm = qhm + ME;
    unsigned short* vth = khm + ME;
    unsigned short* cx  = vth + ME;
    const int gblocks = (MTOK / 128) * (HID / 128);  // 512

    gemm_bt<float, 1><<<gblocks, blk, 0, stream>>>(query, Wq, bq, qhm, MTOK, HID, HID);
    gemm_bt<float, 1><<<gblocks, blk, 0, stream>>>(key_, Wk, bk, khm, MTOK, HID, HID);
    gemm_bt<float, 2><<<gblocks, blk, 0, stream>>>(value, Wv, bv, vth, MTOK, HID, HID);
    attn_v5<<<BB * NHEAD * (SS / 128), blk512, 0, stream>>>(qhm, khm, vth, mask, cx);
    gemm_bt<unsigned short, 0><<<gblocks, blk, 0, stream>>>(cx, Wo, bo, out, MTOK, HID, HID);
  }
}